// Round 1
// baseline (806.789 us; speedup 1.0000x reference)
//
#include <hip/hip_runtime.h>

typedef unsigned short u16;
typedef __attribute__((ext_vector_type(8))) short s16x8;
typedef __attribute__((ext_vector_type(4))) float f32x4;

__device__ __forceinline__ u16 f2bf(float f) {
  unsigned u = __builtin_bit_cast(unsigned, f);
  return (u16)((u + 0x7fffu + ((u >> 16) & 1u)) >> 16);  // RNE
}
__device__ __forceinline__ float bf2f(u16 h) {
  return __builtin_bit_cast(float, (unsigned)h << 16);
}

// async global->LDS, 16B per lane; LDS dest is wave-uniform base + lane*16
#define GLOAD16(gp, lp) __builtin_amdgcn_global_load_lds( \
    (__attribute__((address_space(1))) void*)(gp),        \
    (__attribute__((address_space(3))) void*)(lp), 16, 0, 0)

// ---------------------------------------------------------------------------
// 128x128-tile bf16 GEMM, B^T layout:  C[m][n] = sum_k A[m][k] * Bt[n][k]
// BK=32, 256 threads (4 waves, 2x2 wave grid, 64x64 per wave, 4x4 fragments).
// biasMode: 0 none, 1 bias[col], 2 bias[row].  M,N multiples of 128, K of 32.
// ---------------------------------------------------------------------------
template<bool OUT_F32>
__global__ __launch_bounds__(256, 3) void gemm_bt(
    const u16* __restrict__ A, int lda, long sA,
    const u16* __restrict__ Bt, int ldb, long sB,
    void* __restrict__ Cv, int ldc, long sC,
    const float* __restrict__ bias, int biasMode, float scale, int K)
{
  __shared__ u16 lsA[128 * 32];
  __shared__ u16 lsB[128 * 32];

  const int t = threadIdx.x;
  const int wave = t >> 6, lane = t & 63;
  const long brow = (long)blockIdx.x * 128;
  const long bcol = (long)blockIdx.y * 128;
  const int z = blockIdx.z;
  A  += z * sA;
  Bt += z * sB;

  // staging: linear [row][k] tile, 64B per row; pass0 rows 0..63, pass1 64..127
  const int srow = t >> 2;           // 0..63
  const int skb  = (t & 3) * 16;     // byte offset within row
  const char* gA0 = (const char*)(A  + (brow + srow)      * (long)lda) + skb;
  const char* gA1 = (const char*)(A  + (brow + 64 + srow) * (long)lda) + skb;
  const char* gB0 = (const char*)(Bt + (bcol + srow)      * (long)ldb) + skb;
  const char* gB1 = (const char*)(Bt + (bcol + 64 + srow) * (long)ldb) + skb;
  u16* lA0 = &lsA[(wave * 64) * 8];
  u16* lA1 = &lsA[(256 + wave * 64) * 8];
  u16* lB0 = &lsB[(wave * 64) * 8];
  u16* lB1 = &lsB[(256 + wave * 64) * 8];

  const int wr = (wave >> 1) * 64;
  const int wc = (wave & 1) * 64;
  const int ar = lane & 15;          // fragment row/col within 16
  const int ak = (lane >> 4) * 8;    // k sub-block

  f32x4 acc[4][4];
  #pragma unroll
  for (int i = 0; i < 4; ++i)
    #pragma unroll
    for (int j = 0; j < 4; ++j)
      acc[i][j] = (f32x4){0.f, 0.f, 0.f, 0.f};

  for (int k0 = 0; k0 < K; k0 += 32) {
    GLOAD16(gA0, lA0);
    GLOAD16(gA1, lA1);
    GLOAD16(gB0, lB0);
    GLOAD16(gB1, lB1);
    gA0 += 64; gA1 += 64; gB0 += 64; gB1 += 64;
    __syncthreads();   // drains vmcnt -> staged data visible

    s16x8 a[4], b[4];
    #pragma unroll
    for (int m = 0; m < 4; ++m)
      a[m] = *(const s16x8*)&lsA[(wr + m * 16 + ar) * 32 + ak];
    #pragma unroll
    for (int n = 0; n < 4; ++n)
      b[n] = *(const s16x8*)&lsB[(wc + n * 16 + ar) * 32 + ak];
    #pragma unroll
    for (int m = 0; m < 4; ++m)
      #pragma unroll
      for (int n = 0; n < 4; ++n)
        acc[m][n] = __builtin_amdgcn_mfma_f32_16x16x32_bf16(a[m], b[n], acc[m][n], 0, 0, 0);
    __syncthreads();
  }

  // epilogue: C/D layout col=lane&15, row=(lane>>4)*4+r
  const long row0 = brow + wr + (lane >> 4) * 4;
  const long col0 = bcol + wc + (lane & 15);
  #pragma unroll
  for (int m = 0; m < 4; ++m) {
    #pragma unroll
    for (int n = 0; n < 4; ++n) {
      #pragma unroll
      for (int r = 0; r < 4; ++r) {
        long row = row0 + m * 16 + r;
        long col = col0 + n * 16;
        float v = acc[m][n][r] * scale;
        if (biasMode == 1) v += bias[col];
        else if (biasMode == 2) v += bias[row];
        if constexpr (OUT_F32)
          ((float*)Cv)[(long)z * sC + row * (long)ldc + col] = v;
        else
          ((u16*)Cv)[(long)z * sC + row * (long)ldc + col] = f2bf(v);
      }
    }
  }
}

// fp32 -> bf16, 4 elems/thread, exact grid
__global__ __launch_bounds__(256) void cvt_x(const float4* __restrict__ in,
                                             u16* __restrict__ out) {
  long i = (long)blockIdx.x * 256 + threadIdx.x;
  float4 v = in[i];
  uint2 o;
  o.x = (unsigned)f2bf(v.x) | ((unsigned)f2bf(v.y) << 16);
  o.y = (unsigned)f2bf(v.z) | ((unsigned)f2bf(v.w) << 16);
  *(uint2*)(out + i * 4) = o;
}

// W[768][768] fp32 -> WT[768][768] bf16 (coalesced writes, L2-cached reads)
__global__ __launch_bounds__(256) void cvt_trw(const float* __restrict__ W,
                                               u16* __restrict__ WT) {
  int idx = blockIdx.x * 256 + threadIdx.x;   // = h*768 + d
  int h = idx / 768;
  int d = idx - h * 768;
  WT[idx] = f2bf(W[d * 768 + h]);
}

// in-place row softmax over 2048-wide bf16 rows; one block per row
__global__ __launch_bounds__(256) void softmax_rows(u16* __restrict__ S) {
  const int t = threadIdx.x;
  const int wave = t >> 6, lane = t & 63;
  u16* row = S + (long)blockIdx.x * 2048;
  s16x8 v = *(const s16x8*)(row + t * 8);
  float f[8];
  #pragma unroll
  for (int j = 0; j < 8; ++j) f[j] = bf2f((u16)v[j]);
  float mx = f[0];
  #pragma unroll
  for (int j = 1; j < 8; ++j) mx = fmaxf(mx, f[j]);
  #pragma unroll
  for (int off = 32; off > 0; off >>= 1) mx = fmaxf(mx, __shfl_xor(mx, off, 64));
  __shared__ float smax[4];
  __shared__ float ssum[4];
  if (lane == 0) smax[wave] = mx;
  __syncthreads();
  mx = fmaxf(fmaxf(smax[0], smax[1]), fmaxf(smax[2], smax[3]));
  float s = 0.f;
  #pragma unroll
  for (int j = 0; j < 8; ++j) { f[j] = __expf(f[j] - mx); s += f[j]; }
  #pragma unroll
  for (int off = 32; off > 0; off >>= 1) s += __shfl_xor(s, off, 64);
  if (lane == 0) ssum[wave] = s;
  __syncthreads();
  s = (ssum[0] + ssum[1]) + (ssum[2] + ssum[3]);
  float inv = 1.f / s;
  s16x8 o;
  #pragma unroll
  for (int j = 0; j < 8; ++j) o[j] = (short)f2bf(f[j] * inv);
  *(s16x8*)(row + t * 8) = o;
}

extern "C" void kernel_launch(void* const* d_in, const int* in_sizes, int n_in,
                              void* d_out, int out_size, void* d_ws, size_t ws_size,
                              hipStream_t stream) {
  const float* x_to   = (const float*)d_in[0];
  const float* x_from = (const float*)d_in[1];
  const float* Wq = (const float*)d_in[2];
  const float* bq = (const float*)d_in[3];
  const float* Wk = (const float*)d_in[4];
  const float* bk = (const float*)d_in[5];
  const float* Wv = (const float*)d_in[6];
  const float* bv = (const float*)d_in[7];

  const long NX = 16L * 2048 * 768;   // 25,165,824 elements per activation
  const long NW = 768L * 768;

  // workspace layout (285.2 MB):
  //   [0)           Qb, Kb, Vt  (bf16, live to the end)      151.0 MB
  //   [3*NX)        union{ xtb,xfb,WqT,WkT,WvT  |  Sb }      134.2 MB
  u16* Qb  = (u16*)d_ws;
  u16* Kb  = Qb + NX;
  u16* Vt  = Kb + NX;                 // [768][32768] = V^T, batches in columns
  u16* reg2 = Vt + NX;
  u16* Sb  = reg2;                    // [16][2048][2048]
  u16* xtb = reg2;
  u16* xfb = xtb + NX;
  u16* WqT = xfb + NX;
  u16* WkT = WqT + NW;
  u16* WvT = WkT + NW;

  // 1. convert activations + weights (transposed) to bf16
  cvt_x<<<24576, 256, 0, stream>>>((const float4*)x_to, xtb);
  cvt_x<<<24576, 256, 0, stream>>>((const float4*)x_from, xfb);
  cvt_trw<<<2304, 256, 0, stream>>>(Wq, WqT);
  cvt_trw<<<2304, 256, 0, stream>>>(Wk, WkT);
  cvt_trw<<<2304, 256, 0, stream>>>(Wv, WvT);

  dim3 blk(256);
  // 2. projections:  Q = x_to@Wq+bq,  K = x_from@Wk+bk  ([32768,768] bf16)
  gemm_bt<false><<<dim3(256, 6, 1), blk, 0, stream>>>(
      xtb, 768, 0, WqT, 768, 0, Qb, 768, 0, bq, 1, 1.f, 768);
  gemm_bt<false><<<dim3(256, 6, 1), blk, 0, stream>>>(
      xfb, 768, 0, WkT, 768, 0, Kb, 768, 0, bk, 1, 1.f, 768);
  //    V^T = Wv^T @ x_from^T + bv  -> Vt[768][32768]
  gemm_bt<false><<<dim3(6, 256, 1), blk, 0, stream>>>(
      WvT, 768, 0, xfb, 768, 0, Vt, 32768, 0, bv, 2, 1.f, 768);

  // 3. S = Q K^T / sqrt(768)  per batch  ([2048,2048] bf16 each)
  gemm_bt<false><<<dim3(16, 16, 16), blk, 0, stream>>>(
      Qb, 768, 2048L * 768, Kb, 768, 2048L * 768,
      Sb, 2048, 2048L * 2048, nullptr, 0, 0.03608439182435161f, 768);

  // 4. softmax rows in place
  softmax_rows<<<32768, 256, 0, stream>>>(Sb);

  // 5. O = P @ V  per batch  (A=P [2048,2048], Bt=Vt+b*2048 ldb=32768) -> fp32
  gemm_bt<true><<<dim3(16, 6, 16), blk, 0, stream>>>(
      Sb, 2048, 2048L * 2048, Vt, 32768, 2048,
      (float*)d_out, 768, 2048L * 768, nullptr, 0, 1.f, 2048);
}

// Round 2
// 763.033 us; speedup vs baseline: 1.0573x; 1.0573x over previous
//
#include <hip/hip_runtime.h>

typedef unsigned short u16;
typedef __attribute__((ext_vector_type(8))) short s16x8;
typedef __attribute__((ext_vector_type(4))) float f32x4;

__device__ __forceinline__ u16 f2bf(float f) {
  unsigned u = __builtin_bit_cast(unsigned, f);
  return (u16)((u + 0x7fffu + ((u >> 16) & 1u)) >> 16);  // RNE
}
__device__ __forceinline__ float bf2f(u16 h) {
  return __builtin_bit_cast(float, (unsigned)h << 16);
}

// async global->LDS, 16B/lane; LDS dest = wave-uniform base + lane*16 (linear)
#define GLOAD16(gp, lp) __builtin_amdgcn_global_load_lds( \
    (__attribute__((address_space(1))) void*)(gp),        \
    (__attribute__((address_space(3))) void*)(lp), 16, 0, 0)

// stage one 128-row half-tile (2 rounds of 64 rows); p auto-advances one K-tile
#define STG(p, ldx, off) do { \
    GLOAD16(p, ldst + (off)); \
    GLOAD16(p + 64 * (ldx), ldst + (off) + 8192); \
    p += 128; } while (0)

#define LD8(off) (*(const s16x8*)(ldsb + (off)))

#define MFMA2(mi, n) \
    acc[mi][n] = __builtin_amdgcn_mfma_f32_16x16x32_bf16(af[((mi)&3)*2],   bf[(n)*2],   acc[mi][n], 0,0,0); \
    acc[mi][n] = __builtin_amdgcn_mfma_f32_16x16x32_bf16(af[((mi)&3)*2+1], bf[(n)*2+1], acc[mi][n], 0,0,0);

#define PH_MID() __builtin_amdgcn_s_barrier(); \
    asm volatile("s_waitcnt lgkmcnt(0)" ::: "memory"); \
    __builtin_amdgcn_s_setprio(1)
#define PH_END() __builtin_amdgcn_s_setprio(0)

// One K-tile = 4 phases. Quadrant (m-half, n-half). Stage schedule (derived,
// all read/write overlaps barrier-separated):
//   ph1: stage A1(t+1) -> other buf   (A-half1 of prev tile last read ph3 + ph4 barrier)
//   ph3: stage B0(t+2) -> this buf    (B-half0 of THIS tile last read ph2)
//   ph4: stage B1(t+2), A0(t+2)       (B-half1 read<=ph2, A-half0 read<=ph3)
// Boundary: 3 half-tiles (6 loads) in flight -> s_waitcnt vmcnt(6).
#define KTILE(BOFF, OOFF, SA1, SB2, VMW) do { \
  af[0]=LD8((BOFF)+aoff0);      af[1]=LD8((BOFF)+aoff1); \
  af[2]=LD8((BOFF)+aoff0+2048); af[3]=LD8((BOFF)+aoff1+2048); \
  af[4]=LD8((BOFF)+aoff0+4096); af[5]=LD8((BOFF)+aoff1+4096); \
  af[6]=LD8((BOFF)+aoff0+6144); af[7]=LD8((BOFF)+aoff1+6144); \
  bf[0]=LD8((BOFF)+boff0);      bf[1]=LD8((BOFF)+boff1); \
  bf[2]=LD8((BOFF)+boff0+2048); bf[3]=LD8((BOFF)+boff1+2048); \
  if (SA1) STG(pA1, ldab, (OOFF) + 16384); \
  asm volatile("s_waitcnt lgkmcnt(8)" ::: "memory"); \
  PH_MID(); \
  MFMA2(0,0) MFMA2(1,0) MFMA2(2,0) MFMA2(3,0) \
  MFMA2(0,1) MFMA2(1,1) MFMA2(2,1) MFMA2(3,1) \
  PH_END(); __builtin_amdgcn_s_barrier(); \
  bf[4]=LD8((BOFF)+boff0+4096); bf[5]=LD8((BOFF)+boff1+4096); \
  bf[6]=LD8((BOFF)+boff0+6144); bf[7]=LD8((BOFF)+boff1+6144); \
  PH_MID(); \
  MFMA2(0,2) MFMA2(1,2) MFMA2(2,2) MFMA2(3,2) \
  MFMA2(0,3) MFMA2(1,3) MFMA2(2,3) MFMA2(3,3) \
  PH_END(); __builtin_amdgcn_s_barrier(); \
  af[0]=LD8((BOFF)+aoff0+8192);  af[1]=LD8((BOFF)+aoff1+8192); \
  af[2]=LD8((BOFF)+aoff0+10240); af[3]=LD8((BOFF)+aoff1+10240); \
  af[4]=LD8((BOFF)+aoff0+12288); af[5]=LD8((BOFF)+aoff1+12288); \
  af[6]=LD8((BOFF)+aoff0+14336); af[7]=LD8((BOFF)+aoff1+14336); \
  if (SB2) STG(pB0, ldbb, (BOFF) + 32768); \
  PH_MID(); \
  MFMA2(4,0) MFMA2(5,0) MFMA2(6,0) MFMA2(7,0) \
  MFMA2(4,1) MFMA2(5,1) MFMA2(6,1) MFMA2(7,1) \
  PH_END(); __builtin_amdgcn_s_barrier(); \
  if (SB2) { STG(pB1, ldbb, (BOFF) + 49152); STG(pA0, ldab, (BOFF)); } \
  PH_MID(); \
  MFMA2(4,2) MFMA2(5,2) MFMA2(6,2) MFMA2(7,2) \
  MFMA2(4,3) MFMA2(5,3) MFMA2(6,3) MFMA2(7,3) \
  PH_END(); \
  VMW; \
  __builtin_amdgcn_s_barrier(); \
} while (0)

// ---------------------------------------------------------------------------
// 256x256-tile bf16 GEMM, 8-phase schedule (T1+T2+T3+T4+T5).
// C[m][n] = sum_k A[m][k]*Bt[n][k].  512 threads = 8 waves (2M x 4N),
// per-wave 128x64 output. BK=64, double-buffered 128 KiB LDS, XOR-slot swizzle.
// M,N multiples of 256; K multiple of 128 (>=256).
// ---------------------------------------------------------------------------
template<bool OUT_F32>
__global__ __launch_bounds__(512, 2) void gemm256(
    const u16* __restrict__ A, int lda, long sA,
    const u16* __restrict__ Bt, int ldb, long sB,
    void* __restrict__ Cv, int ldc, long sC,
    const float* __restrict__ bias, long biasStride, int biasMode,
    float scale, int K)
{
  __shared__ __align__(128) char ldsb[131072];   // [buf][A 32K | B 32K]
  const int tid = threadIdx.x;
  const int w = tid >> 6, l = tid & 63;
  const int wm = w >> 2, wn = w & 3;
  const int q = l >> 4, fr = l & 15;

  // bijective XCD swizzle on flattened (x,y)
  int bx, by;
  { int gx = gridDim.x; int nwg = gx * (int)gridDim.y;
    int id = blockIdx.y * gx + blockIdx.x;
    int qq = nwg >> 3, r = nwg & 7, xc = id & 7, ix = id >> 3;
    int swz = (xc < r ? xc * (qq + 1) : r * (qq + 1) + (xc - r) * qq) + ix;
    bx = swz % gx; by = swz / gx; }
  const long brow = (long)bx * 256, bcol = (long)by * 256;
  const int z = blockIdx.z;
  A += (long)z * sA; Bt += (long)z * sB;
  if (biasMode) bias += (long)z * biasStride;

  const long ldab = (long)lda * 2, ldbb = (long)ldb * 2;
  // staging: wave w covers rows w*8..w*8+7 per 64-row round; source slot
  // pre-swizzled so linear LDS write == swizzled layout (rule #21)
  const int rih = w * 8 + (l >> 3);
  const int sl  = ((l & 7) ^ (l >> 3)) * 16;
  const char* pA0 = (const char*)A  + (brow + rih) * ldab + sl;
  const char* pA1 = pA0 + 128 * ldab;
  const char* pB0 = (const char*)Bt + (bcol + rih) * ldbb + sl;
  const char* pB1 = pB0 + 128 * ldbb;
  char* ldst = ldsb + w * 1024;

  // read offsets: row r slot s holds global slot s^(r&7); want slot ks*4+q
  const int sw = fr & 7;
  const int arow_o = (wm * 128 + fr) * 128;
  const int brow_o = (wn * 64 + fr) * 128 + 32768;
  const int aoff0 = arow_o + ((q)     ^ sw) * 16;
  const int aoff1 = arow_o + ((4 + q) ^ sw) * 16;
  const int boff0 = brow_o + ((q)     ^ sw) * 16;
  const int boff1 = brow_o + ((4 + q) ^ sw) * 16;

  f32x4 acc[8][4];
  #pragma unroll
  for (int i = 0; i < 8; ++i)
    #pragma unroll
    for (int j = 0; j < 4; ++j) acc[i][j] = (f32x4){0.f, 0.f, 0.f, 0.f};
  s16x8 af[8], bf[8];

  // prologue: tile0 fully + {B0,B1,A0} of tile1 -> 3 halves in flight
  STG(pA0, ldab, 0);
  STG(pA1, ldab, 16384);
  STG(pB0, ldbb, 32768);
  STG(pB1, ldbb, 49152);
  asm volatile("s_waitcnt vmcnt(4)" ::: "memory");
  STG(pB0, ldbb, 65536 + 32768);
  STG(pB1, ldbb, 65536 + 49152);
  STG(pA0, ldab, 65536);
  asm volatile("s_waitcnt vmcnt(6)" ::: "memory");
  __builtin_amdgcn_s_barrier();

  const int half_iters = (K >> 7) - 1;   // NT/2 - 1, NT = K/64 (even)
  for (int it = 0; it < half_iters; ++it) {
    KTILE(0,     65536, 1, 1, asm volatile("s_waitcnt vmcnt(6)" ::: "memory"));
    KTILE(65536, 0,     1, 1, asm volatile("s_waitcnt vmcnt(6)" ::: "memory"));
  }
  KTILE(0,     65536, 1, 0, asm volatile("s_waitcnt vmcnt(0)" ::: "memory"));
  KTILE(65536, 0,     0, 0, ((void)0));

  // epilogue: C/D layout col=lane&15, row=(lane>>4)*4+rr
  const long row0 = brow + wm * 128 + q * 4;
  const long col0 = bcol + wn * 64 + fr;
  #pragma unroll
  for (int mi = 0; mi < 8; ++mi) {
    #pragma unroll
    for (int n = 0; n < 4; ++n) {
      #pragma unroll
      for (int rr = 0; rr < 4; ++rr) {
        long row = row0 + mi * 16 + rr;
        long col = col0 + n * 16;
        float v = acc[mi][n][rr] * scale;
        if (biasMode == 1) v += bias[col];
        else if (biasMode == 2) v += bias[row];
        if constexpr (OUT_F32)
          ((float*)Cv)[(long)z * sC + row * (long)ldc + col] = v;
        else
          ((u16*)Cv)[(long)z * sC + row * (long)ldc + col] = f2bf(v);
      }
    }
  }
}

// fp32 -> bf16, both activations in one launch (blockIdx.y selects)
__global__ __launch_bounds__(256) void cvt_x2(const float4* __restrict__ xt,
                                              const float4* __restrict__ xf,
                                              u16* __restrict__ out, long NX) {
  const float4* src = blockIdx.y ? xf : xt;
  u16* dst = out + (long)blockIdx.y * NX;
  long i = (long)blockIdx.x * 256 + threadIdx.x;
  float4 v = src[i];
  uint2 o;
  o.x = (unsigned)f2bf(v.x) | ((unsigned)f2bf(v.y) << 16);
  o.y = (unsigned)f2bf(v.z) | ((unsigned)f2bf(v.w) << 16);
  *(uint2*)(dst + i * 4) = o;
}

// W[768][768] fp32 -> WT[768][768] bf16, all three weights in one launch
__global__ __launch_bounds__(256) void cvt_w3(const float* __restrict__ W0,
                                              const float* __restrict__ W1,
                                              const float* __restrict__ W2,
                                              u16* __restrict__ WT) {
  const float* W = blockIdx.y == 0 ? W0 : (blockIdx.y == 1 ? W1 : W2);
  u16* dst = WT + (long)blockIdx.y * 589824;
  int idx = blockIdx.x * 256 + threadIdx.x;
  int h = idx / 768, d = idx - h * 768;
  dst[idx] = f2bf(W[d * 768 + h]);
}

__global__ __launch_bounds__(256) void pack_bias(const float* __restrict__ bq,
                                                 const float* __restrict__ bk,
                                                 float* __restrict__ out) {
  int i = blockIdx.x * 256 + threadIdx.x;   // grid 6*256 = 1536
  out[i] = i < 768 ? bq[i] : bk[i - 768];
}

// in-place row softmax over 2048-wide bf16 rows; one block per row
__global__ __launch_bounds__(256) void softmax_rows(u16* __restrict__ S) {
  const int t = threadIdx.x;
  const int wave = t >> 6, lane = t & 63;
  u16* row = S + (long)blockIdx.x * 2048;
  s16x8 v = *(const s16x8*)(row + t * 8);
  float f[8];
  #pragma unroll
  for (int j = 0; j < 8; ++j) f[j] = bf2f((u16)v[j]);
  float mx = f[0];
  #pragma unroll
  for (int j = 1; j < 8; ++j) mx = fmaxf(mx, f[j]);
  #pragma unroll
  for (int off = 32; off > 0; off >>= 1) mx = fmaxf(mx, __shfl_xor(mx, off, 64));
  __shared__ float smax[4];
  __shared__ float ssum[4];
  if (lane == 0) smax[wave] = mx;
  __syncthreads();
  mx = fmaxf(fmaxf(smax[0], smax[1]), fmaxf(smax[2], smax[3]));
  float s = 0.f;
  #pragma unroll
  for (int j = 0; j < 8; ++j) { f[j] = __expf(f[j] - mx); s += f[j]; }
  #pragma unroll
  for (int off = 32; off > 0; off >>= 1) s += __shfl_xor(s, off, 64);
  if (lane == 0) ssum[wave] = s;
  __syncthreads();
  s = (ssum[0] + ssum[1]) + (ssum[2] + ssum[3]);
  float inv = 1.f / s;
  s16x8 o;
  #pragma unroll
  for (int j = 0; j < 8; ++j) o[j] = (short)f2bf(f[j] * inv);
  *(s16x8*)(row + t * 8) = o;
}

extern "C" void kernel_launch(void* const* d_in, const int* in_sizes, int n_in,
                              void* d_out, int out_size, void* d_ws, size_t ws_size,
                              hipStream_t stream) {
  const float* x_to   = (const float*)d_in[0];
  const float* x_from = (const float*)d_in[1];
  const float* Wq = (const float*)d_in[2];
  const float* bq = (const float*)d_in[3];
  const float* Wk = (const float*)d_in[4];
  const float* bk = (const float*)d_in[5];
  const float* Wv = (const float*)d_in[6];
  const float* bv = (const float*)d_in[7];

  const long NX = 16L * 2048 * 768;
  const long NW = 768L * 768;

  // ws layout: [Qb NX][Kb NX][Vt NX] then union{ xtb NX, xfb NX, WqT/WkT/WvT 3NW,
  // bqk 1536 f32  |  Sb 16*2048*2048 } (bias region dies before S is written)
  u16* Qb  = (u16*)d_ws;
  u16* Kb  = Qb + NX;
  u16* Vt  = Kb + NX;                 // [768][32768] = V^T per-batch columns
  u16* reg2 = Vt + NX;
  u16* Sb  = reg2;
  u16* xtb = reg2;
  u16* xfb = xtb + NX;
  u16* WqT = xfb + NX;                // WqT,WkT,WvT contiguous
  float* bqk = (float*)(WqT + 3 * NW);

  cvt_x2<<<dim3(24576, 2), 256, 0, stream>>>((const float4*)x_to,
                                             (const float4*)x_from, xtb, NX);
  cvt_w3<<<dim3(2304, 3), 256, 0, stream>>>(Wq, Wk, Wv, WqT);
  pack_bias<<<6, 256, 0, stream>>>(bq, bk, bqk);

  dim3 blk(512);
  // Q = x_to@Wq+bq and K = x_from@Wk+bk in one batched launch (z=0:Q, z=1:K)
  gemm256<false><<<dim3(128, 3, 2), blk, 0, stream>>>(
      xtb, 768, NX, WqT, 768, NW, Qb, 768, NX, bqk, 768, 1, 1.f, 768);
  // V^T = Wv^T @ x_from^T + bv  -> Vt[768][32768]
  gemm256<false><<<dim3(3, 128, 1), blk, 0, stream>>>(
      WqT + 2 * NW, 768, 0, xfb, 768, 0, Vt, 32768, 0, bv, 0, 2, 1.f, 768);
  // S = Q K^T / sqrt(768) per batch
  gemm256<false><<<dim3(8, 8, 16), blk, 0, stream>>>(
      Qb, 768, 2048L * 768, Kb, 768, 2048L * 768,
      Sb, 2048, 2048L * 2048, nullptr, 0, 0, 0.036084391824351615f, 768);
  softmax_rows<<<32768, 256, 0, stream>>>(Sb);
  // O = P @ V per batch -> fp32 out
  gemm256<true><<<dim3(8, 3, 16), blk, 0, stream>>>(
      Sb, 2048, 2048L * 2048, Vt, 32768, 2048,
      (float*)d_out, 768, 2048L * 768, nullptr, 0, 0, 1.f, 2048);
}

// Round 4
// 761.846 us; speedup vs baseline: 1.0590x; 1.0016x over previous
//
#include <hip/hip_runtime.h>

typedef unsigned short u16;
typedef __attribute__((ext_vector_type(8))) short s16x8;
typedef __attribute__((ext_vector_type(4))) float f32x4;

__device__ __forceinline__ u16 f2bf(float f) {
  unsigned u = __builtin_bit_cast(unsigned, f);
  return (u16)((u + 0x7fffu + ((u >> 16) & 1u)) >> 16);  // RNE
}
__device__ __forceinline__ float bf2f(u16 h) {
  return __builtin_bit_cast(float, (unsigned)h << 16);
}

// async global->LDS, 16B/lane; LDS dest = wave-uniform base + lane*16 (linear)
#define GLOAD16(gp, lp) __builtin_amdgcn_global_load_lds( \
    (__attribute__((address_space(1))) void*)(gp),        \
    (__attribute__((address_space(3))) void*)(lp), 16, 0, 0)

// stage one 128-row half-tile (2 rounds of 64 rows); p auto-advances one K-tile
#define STG(p, ldx, off) do { \
    GLOAD16(p, ldst + (off)); \
    GLOAD16(p + 64 * (ldx), ldst + (off) + 8192); \
    p += 128; } while (0)

#define LD8(off) (*(const s16x8*)(ldsb + (off)))

#define MF(a, b, c) __builtin_amdgcn_mfma_f32_16x16x32_bf16(a, b, c, 0, 0, 0)

// 16 MFMAs of one C-quadrant (rows MB..MB+3, cols NB..NB+1) over K=64,
// ordered k-half-0 across all 8 accumulators then k-half-1: dependency
// distance 8 (was 1 in round 2 -> latency-bound MFMA pairs).
#define PH_MFMA(MB, NB) do { \
  acc[(MB)+0][(NB)]   = MF(af[0], bf[(NB)*2],   acc[(MB)+0][(NB)]); \
  acc[(MB)+1][(NB)]   = MF(af[2], bf[(NB)*2],   acc[(MB)+1][(NB)]); \
  acc[(MB)+2][(NB)]   = MF(af[4], bf[(NB)*2],   acc[(MB)+2][(NB)]); \
  acc[(MB)+3][(NB)]   = MF(af[6], bf[(NB)*2],   acc[(MB)+3][(NB)]); \
  acc[(MB)+0][(NB)+1] = MF(af[0], bf[(NB)*2+2], acc[(MB)+0][(NB)+1]); \
  acc[(MB)+1][(NB)+1] = MF(af[2], bf[(NB)*2+2], acc[(MB)+1][(NB)+1]); \
  acc[(MB)+2][(NB)+1] = MF(af[4], bf[(NB)*2+2], acc[(MB)+2][(NB)+1]); \
  acc[(MB)+3][(NB)+1] = MF(af[6], bf[(NB)*2+2], acc[(MB)+3][(NB)+1]); \
  acc[(MB)+0][(NB)]   = MF(af[1], bf[(NB)*2+1], acc[(MB)+0][(NB)]); \
  acc[(MB)+1][(NB)]   = MF(af[3], bf[(NB)*2+1], acc[(MB)+1][(NB)]); \
  acc[(MB)+2][(NB)]   = MF(af[5], bf[(NB)*2+1], acc[(MB)+2][(NB)]); \
  acc[(MB)+3][(NB)]   = MF(af[7], bf[(NB)*2+1], acc[(MB)+3][(NB)]); \
  acc[(MB)+0][(NB)+1] = MF(af[1], bf[(NB)*2+3], acc[(MB)+0][(NB)+1]); \
  acc[(MB)+1][(NB)+1] = MF(af[3], bf[(NB)*2+3], acc[(MB)+1][(NB)+1]); \
  acc[(MB)+2][(NB)+1] = MF(af[5], bf[(NB)*2+3], acc[(MB)+2][(NB)+1]); \
  acc[(MB)+3][(NB)+1] = MF(af[7], bf[(NB)*2+3], acc[(MB)+3][(NB)+1]); \
} while (0)

#define PH_MID() __builtin_amdgcn_s_barrier(); \
    asm volatile("s_waitcnt lgkmcnt(0)" ::: "memory"); \
    __builtin_amdgcn_s_setprio(1)
#define PH_END() __builtin_amdgcn_s_setprio(0)

// One K-tile = 4 phases. Stage schedule (all overlaps barrier-separated):
//   ph1: stage A1(t+1) -> other buf; ph3: B0(t+2) -> this buf; ph4: B1,A0(t+2).
// Boundary: 3 half-tiles (6 loads) in flight -> s_waitcnt vmcnt(6).
#define KTILE(BOFF, OOFF, SA1, SB2, VMW) do { \
  af[0]=LD8((BOFF)+aoff0);      af[1]=LD8((BOFF)+aoff1); \
  af[2]=LD8((BOFF)+aoff0+2048); af[3]=LD8((BOFF)+aoff1+2048); \
  af[4]=LD8((BOFF)+aoff0+4096); af[5]=LD8((BOFF)+aoff1+4096); \
  af[6]=LD8((BOFF)+aoff0+6144); af[7]=LD8((BOFF)+aoff1+6144); \
  bf[0]=LD8((BOFF)+boff0);      bf[1]=LD8((BOFF)+boff1); \
  bf[2]=LD8((BOFF)+boff0+2048); bf[3]=LD8((BOFF)+boff1+2048); \
  if (SA1) STG(pA1, ldab, (OOFF) + 16384); \
  asm volatile("s_waitcnt lgkmcnt(8)" ::: "memory"); \
  PH_MID(); \
  PH_MFMA(0, 0); \
  PH_END(); __builtin_amdgcn_s_barrier(); \
  bf[4]=LD8((BOFF)+boff0+4096); bf[5]=LD8((BOFF)+boff1+4096); \
  bf[6]=LD8((BOFF)+boff0+6144); bf[7]=LD8((BOFF)+boff1+6144); \
  PH_MID(); \
  PH_MFMA(0, 2); \
  PH_END(); __builtin_amdgcn_s_barrier(); \
  af[0]=LD8((BOFF)+aoff0+8192);  af[1]=LD8((BOFF)+aoff1+8192); \
  af[2]=LD8((BOFF)+aoff0+10240); af[3]=LD8((BOFF)+aoff1+10240); \
  af[4]=LD8((BOFF)+aoff0+12288); af[5]=LD8((BOFF)+aoff1+12288); \
  af[6]=LD8((BOFF)+aoff0+14336); af[7]=LD8((BOFF)+aoff1+14336); \
  if (SB2) STG(pB0, ldbb, (BOFF) + 32768); \
  PH_MID(); \
  PH_MFMA(4, 0); \
  PH_END(); __builtin_amdgcn_s_barrier(); \
  if (SB2) { STG(pB1, ldbb, (BOFF) + 49152); STG(pA0, ldab, (BOFF)); } \
  PH_MID(); \
  PH_MFMA(4, 2); \
  PH_END(); \
  VMW; \
  __builtin_amdgcn_s_barrier(); \
} while (0)

// ---------------------------------------------------------------------------
// 256x256-tile bf16 GEMM, 8-phase schedule (T1+T2+T3+T4+T5).
// C[m][n] = sum_k A[m][k]*Bt[n][k].  512 threads = 8 waves (2M x 4N),
// per-wave 128x64 output. BK=64, double-buffered 128 KiB LDS, XOR-slot swizzle.
// M,N multiples of 256; K multiple of 128 (>=256).
// ---------------------------------------------------------------------------
template<bool OUT_F32>
__global__ __launch_bounds__(512, 2) void gemm256(
    const u16* __restrict__ A, int lda, long sA,
    const u16* __restrict__ Bt, int ldb, long sB,
    void* __restrict__ Cv, int ldc, long sC,
    const float* __restrict__ bias, long biasStride, int biasMode,
    float scale, int K)
{
  __shared__ __align__(128) char ldsb[131072];   // [buf][A 32K | B 32K]
  const int tid = threadIdx.x;
  const int w = tid >> 6, l = tid & 63;
  const int wm = w >> 2, wn = w & 3;
  const int q = l >> 4, fr = l & 15;

  // bijective XCD swizzle on flattened (x,y)
  int bx, by;
  { int gx = gridDim.x; int nwg = gx * (int)gridDim.y;
    int id = blockIdx.y * gx + blockIdx.x;
    int qq = nwg >> 3, r = nwg & 7, xc = id & 7, ix = id >> 3;
    int swz = (xc < r ? xc * (qq + 1) : r * (qq + 1) + (xc - r) * qq) + ix;
    bx = swz % gx; by = swz / gx; }
  const long brow = (long)bx * 256, bcol = (long)by * 256;
  const int z = blockIdx.z;
  A += (long)z * sA; Bt += (long)z * sB;
  if (biasMode) bias += (long)z * biasStride;

  const long ldab = (long)lda * 2, ldbb = (long)ldb * 2;
  // staging: wave w covers rows w*8..w*8+7 per 64-row round; source slot
  // pre-swizzled so linear LDS write == swizzled layout
  const int rih = w * 8 + (l >> 3);
  const int sl  = ((l & 7) ^ (l >> 3)) * 16;
  const char* pA0 = (const char*)A  + (brow + rih) * ldab + sl;
  const char* pA1 = pA0 + 128 * ldab;
  const char* pB0 = (const char*)Bt + (bcol + rih) * ldbb + sl;
  const char* pB1 = pB0 + 128 * ldbb;
  char* ldst = ldsb + w * 1024;

  // read offsets: row r slot s holds global slot s^(r&7); want slot ks*4+q
  const int sw = fr & 7;
  const int arow_o = (wm * 128 + fr) * 128;
  const int brow_o = (wn * 64 + fr) * 128 + 32768;
  const int aoff0 = arow_o + ((q)     ^ sw) * 16;
  const int aoff1 = arow_o + ((4 + q) ^ sw) * 16;
  const int boff0 = brow_o + ((q)     ^ sw) * 16;
  const int boff1 = brow_o + ((4 + q) ^ sw) * 16;

  f32x4 acc[8][4];
  #pragma unroll
  for (int i = 0; i < 8; ++i)
    #pragma unroll
    for (int j = 0; j < 4; ++j) acc[i][j] = (f32x4){0.f, 0.f, 0.f, 0.f};
  s16x8 af[8], bf[8];

  // prologue: tile0 fully + {B0,B1,A0} of tile1 -> 3 halves in flight
  STG(pA0, ldab, 0);
  STG(pA1, ldab, 16384);
  STG(pB0, ldbb, 32768);
  STG(pB1, ldbb, 49152);
  asm volatile("s_waitcnt vmcnt(4)" ::: "memory");
  STG(pB0, ldbb, 65536 + 32768);
  STG(pB1, ldbb, 65536 + 49152);
  STG(pA0, ldab, 65536);
  asm volatile("s_waitcnt vmcnt(6)" ::: "memory");
  __builtin_amdgcn_s_barrier();

  const int half_iters = (K >> 7) - 1;   // NT/2 - 1, NT = K/64 (even)
  for (int it = 0; it < half_iters; ++it) {
    KTILE(0,     65536, 1, 1, asm volatile("s_waitcnt vmcnt(6)" ::: "memory"));
    KTILE(65536, 0,     1, 1, asm volatile("s_waitcnt vmcnt(6)" ::: "memory"));
  }
  KTILE(0,     65536, 1, 0, asm volatile("s_waitcnt vmcnt(0)" ::: "memory"));
  KTILE(65536, 0,     0, 0, ((void)0));

  // epilogue: C/D layout col=lane&15, row=(lane>>4)*4+rr
  const long row0 = brow + wm * 128 + q * 4;
  const long col0 = bcol + wn * 64 + fr;
  #pragma unroll
  for (int mi = 0; mi < 8; ++mi) {
    #pragma unroll
    for (int n = 0; n < 4; ++n) {
      #pragma unroll
      for (int rr = 0; rr < 4; ++rr) {
        long row = row0 + mi * 16 + rr;
        long col = col0 + n * 16;
        float v = acc[mi][n][rr] * scale;
        if (biasMode == 1) v += bias[col];
        else if (biasMode == 2) v += bias[row];
        if constexpr (OUT_F32)
          ((float*)Cv)[(long)z * sC + row * (long)ldc + col] = v;
        else
          ((u16*)Cv)[(long)z * sC + row * (long)ldc + col] = f2bf(v);
      }
    }
  }
}

// fp32 -> bf16, both activations in one launch (blockIdx.y selects)
__global__ __launch_bounds__(256) void cvt_x2(const float4* __restrict__ xt,
                                              const float4* __restrict__ xf,
                                              u16* __restrict__ out, long NX) {
  const float4* src = blockIdx.y ? xf : xt;
  u16* dst = out + (long)blockIdx.y * NX;
  long i = (long)blockIdx.x * 256 + threadIdx.x;
  float4 v = src[i];
  uint2 o;
  o.x = (unsigned)f2bf(v.x) | ((unsigned)f2bf(v.y) << 16);
  o.y = (unsigned)f2bf(v.z) | ((unsigned)f2bf(v.w) << 16);
  *(uint2*)(dst + i * 4) = o;
}

// W[768][768] fp32 -> WT[768][768] bf16, all three weights in one launch
__global__ __launch_bounds__(256) void cvt_w3(const float* __restrict__ W0,
                                              const float* __restrict__ W1,
                                              const float* __restrict__ W2,
                                              u16* __restrict__ WT) {
  const float* W = blockIdx.y == 0 ? W0 : (blockIdx.y == 1 ? W1 : W2);
  u16* dst = WT + (long)blockIdx.y * 589824;
  int idx = blockIdx.x * 256 + threadIdx.x;
  int h = idx / 768, d = idx - h * 768;
  dst[idx] = f2bf(W[d * 768 + h]);
}

__global__ __launch_bounds__(256) void pack_bias(const float* __restrict__ bq,
                                                 const float* __restrict__ bk,
                                                 float* __restrict__ out) {
  int i = blockIdx.x * 256 + threadIdx.x;   // grid 6*256 = 1536
  out[i] = i < 768 ? bq[i] : bk[i - 768];
}

// in-place row softmax over 2048-wide bf16 rows; one block per row
__global__ __launch_bounds__(256) void softmax_rows(u16* __restrict__ S) {
  const int t = threadIdx.x;
  const int wave = t >> 6, lane = t & 63;
  u16* row = S + (long)blockIdx.x * 2048;
  s16x8 v = *(const s16x8*)(row + t * 8);
  float f[8];
  #pragma unroll
  for (int j = 0; j < 8; ++j) f[j] = bf2f((u16)v[j]);
  float mx = f[0];
  #pragma unroll
  for (int j = 1; j < 8; ++j) mx = fmaxf(mx, f[j]);
  #pragma unroll
  for (int off = 32; off > 0; off >>= 1) mx = fmaxf(mx, __shfl_xor(mx, off, 64));
  __shared__ float smax[4];
  __shared__ float ssum[4];
  if (lane == 0) smax[wave] = mx;
  __syncthreads();
  mx = fmaxf(fmaxf(smax[0], smax[1]), fmaxf(smax[2], smax[3]));
  float s = 0.f;
  #pragma unroll
  for (int j = 0; j < 8; ++j) { f[j] = __expf(f[j] - mx); s += f[j]; }
  #pragma unroll
  for (int off = 32; off > 0; off >>= 1) s += __shfl_xor(s, off, 64);
  if (lane == 0) ssum[wave] = s;
  __syncthreads();
  s = (ssum[0] + ssum[1]) + (ssum[2] + ssum[3]);
  float inv = 1.f / s;
  s16x8 o;
  #pragma unroll
  for (int j = 0; j < 8; ++j) o[j] = (short)f2bf(f[j] * inv);
  *(s16x8*)(row + t * 8) = o;
}

extern "C" void kernel_launch(void* const* d_in, const int* in_sizes, int n_in,
                              void* d_out, int out_size, void* d_ws, size_t ws_size,
                              hipStream_t stream) {
  const float* x_to   = (const float*)d_in[0];
  const float* x_from = (const float*)d_in[1];
  const float* Wq = (const float*)d_in[2];
  const float* bq = (const float*)d_in[3];
  const float* Wk = (const float*)d_in[4];
  const float* bk = (const float*)d_in[5];
  const float* Wv = (const float*)d_in[6];
  const float* bv = (const float*)d_in[7];

  const long NX = 16L * 2048 * 768;
  const long NW = 768L * 768;

  // Vt per-batch [16][768][ldv]; ldv=2176 -> row stride 4352B = 34 x 128B
  // (gcd(34,2048)=2 -> full L2 set coverage; round-2's ldb=32768 put every
  // staged B row in 4 L2 sets = guaranteed conflict-miss). Fallback if ws
  // is tight.
  long ldv = 2176;
  {
    long need = (2 * NX + 16L * 768 * ldv + 16L * 2048 * 2048) * 2;
    if (need > (long)ws_size) ldv = 2048;
  }
  const long VT = 16L * 768 * ldv;

  // ws layout: [Qb NX][Kb NX][Vt VT] then union{ xtb NX, xfb NX, W 3NW,
  // bqk 1536 f32  |  Sb 16*2048*2048 }
  u16* Qb  = (u16*)d_ws;
  u16* Kb  = Qb + NX;
  u16* Vt  = Kb + NX;
  u16* reg2 = Vt + VT;
  u16* Sb  = reg2;
  u16* xtb = reg2;
  u16* xfb = xtb + NX;
  u16* WqT = xfb + NX;                // WqT,WkT,WvT contiguous
  float* bqk = (float*)(WqT + 3 * NW);

  cvt_x2<<<dim3(24576, 2), 256, 0, stream>>>((const float4*)x_to,
                                             (const float4*)x_from, xtb, NX);
  cvt_w3<<<dim3(2304, 3), 256, 0, stream>>>(Wq, Wk, Wv, WqT);
  pack_bias<<<6, 256, 0, stream>>>(bq, bk, bqk);

  dim3 blk(512);
  // Q = x_to@Wq+bq and K = x_from@Wk+bk in one batched launch (z=0:Q, z=1:K)
  gemm256<false><<<dim3(128, 3, 2), blk, 0, stream>>>(
      xtb, 768, NX, WqT, 768, NW, Qb, 768, NX, bqk, 768, 1, 1.f, 768);
  // Vt_z = Wv^T @ x_from_z^T + bv  -> [768][ldv] per batch (batched z=16)
  gemm256<false><<<dim3(3, 8, 16), blk, 0, stream>>>(
      WqT + 2 * NW, 768, 0, xfb, 768, 2048L * 768,
      Vt, (int)ldv, 768L * ldv, bv, 0, 2, 1.f, 768);
  // S = Q K^T / sqrt(768) per batch
  gemm256<false><<<dim3(8, 8, 16), blk, 0, stream>>>(
      Qb, 768, 2048L * 768, Kb, 768, 2048L * 768,
      Sb, 2048, 2048L * 2048, nullptr, 0, 0, 0.036084391824351615f, 768);
  softmax_rows<<<32768, 256, 0, stream>>>(Sb);
  // O = P @ V per batch -> fp32 out
  gemm256<true><<<dim3(8, 3, 16), blk, 0, stream>>>(
      Sb, 2048, 2048L * 2048, Vt, (int)ldv, 768L * ldv,
      (float*)d_out, 768, 2048L * 768, nullptr, 0, 0, 1.f, 2048);
}